// Round 3
// baseline (719.038 us; speedup 1.0000x reference)
//
#include <hip/hip_runtime.h>
#include <stdint.h>

typedef unsigned long long ull;

#define TT 2048

// ---------------- compile-time threefry2x32 (JAX semantics) ----------------
struct TF2 { uint32_t x, y; };

constexpr TF2 tf2x32(uint32_t k0, uint32_t k1, uint32_t x0, uint32_t x1) {
  uint32_t ks2 = k0 ^ k1 ^ 0x1BD11BDAu;
  x0 += k0; x1 += k1;
#define TFR_(r) x0 += x1; x1 = __builtin_rotateleft32(x1, r); x1 ^= x0;
  TFR_(13) TFR_(15) TFR_(26) TFR_(6)
  x0 += k1;  x1 += ks2 + 1u;
  TFR_(17) TFR_(29) TFR_(16) TFR_(24)
  x0 += ks2; x1 += k0 + 2u;
  TFR_(13) TFR_(15) TFR_(26) TFR_(6)
  x0 += k0;  x1 += k1 + 3u;
  TFR_(17) TFR_(29) TFR_(16) TFR_(24)
  x0 += k1;  x1 += ks2 + 4u;
  TFR_(13) TFR_(15) TFR_(26) TFR_(6)
  x0 += ks2; x1 += k0 + 5u;
#undef TFR_
  return {x0, x1};
}

struct Half_ { uint32_t a[1024]; uint32_t b[1024]; uint32_t k0, k1; };

constexpr Half_ make_half(uint32_t k0, uint32_t k1) {
  Half_ h{};
  for (int t = 0; t < 1024; ++t) {
    TF2 nk = tf2x32(k0, k1, 0u, 0u);
    TF2 sb = tf2x32(k0, k1, 0u, 1u);
    h.a[t] = sb.x; h.b[t] = sb.y;
    k0 = nk.x; k1 = nk.y;
  }
  h.k0 = k0; h.k1 = k1;
  return h;
}

namespace ckeys {
constexpr Half_ H0 = make_half(0u, 42u);
constexpr Half_ H1 = make_half(H0.k0, H0.k1);
}
__constant__ Half_ dH0 = ckeys::H0;
__constant__ Half_ dH1 = ckeys::H1;

// ---------------- XLA fast-tanh replica ----------------
__device__ __forceinline__ float tanh_xla(float x) {
#pragma clang fp contract(off)
  float ax = fabsf(x);
  float xc = fminf(fmaxf(x, -7.90531110763549805f), 7.90531110763549805f);
  float x2 = xc * xc;
  float p = fmaf(x2, -2.76076847742355e-16f, 2.00018790482477e-13f);
  p = fmaf(x2, p, -8.60467152213735e-11f);
  p = fmaf(x2, p, 5.12229709037114e-08f);
  p = fmaf(x2, p, 1.48572235717979e-05f);
  p = fmaf(x2, p, 6.37261928875436e-04f);
  p = fmaf(x2, p, 4.89352455891786e-03f);
  p = xc * p;
  float q = fmaf(x2, 1.19825839466702e-06f, 1.18534705686654e-04f);
  q = fmaf(x2, q, 2.26843463243900e-03f);
  q = fmaf(x2, q, 4.89352518554385e-03f);
  return (ax < 0.0004f) ? x : (p / q);
}

__device__ __forceinline__ float sig_ref(float z) {
#pragma clang fp contract(off)
  float e = (float)exp(-(double)z);
  return 1.0f / (1.0f + e);
}

__device__ __forceinline__ uint32_t ford(float f) {
  uint32_t x = __float_as_uint(f);
  return (x & 0x80000000u) ? ~x : (x | 0x80000000u);
}
__device__ __forceinline__ float fdec(uint32_t k) {
  uint32_t b = (k & 0x80000000u) ? (k & 0x7fffffffu) : ~k;
  return __uint_as_float(b);
}

// tau = max f32 z with sig_ref(z) <= u  (spike <=> z > tau)
__device__ float find_tau(float u) {
  if (!(u > 0.0f)) return -1.0e30f;
  double zg = log((double)u / (1.0 - (double)u));
  float zgf = (float)zg;
  zgf = fminf(fmaxf(zgf, -90.0f), 90.0f);
  uint32_t kc = ford(zgf);
  uint32_t klo = kc - 96u, khi = kc + 96u;
  if (!(sig_ref(fdec(klo)) <= u)) klo = ford(-95.0f);
  if (!(sig_ref(fdec(khi)) > u))  khi = ford(95.0f);
  while (khi - klo > 1u) {
    uint32_t km = klo + ((khi - klo) >> 1);
    if (sig_ref(fdec(km)) <= u) klo = km; else khi = km;
  }
  return fdec(klo);
}

// ---------------- pre kernel ----------------
__global__ void ap_pre_kernel(const float* __restrict__ V, const float* __restrict__ D,
                              const float* __restrict__ w1, const float* __restrict__ b1,
                              const float* __restrict__ w2, const float* __restrict__ b2,
                              const float* __restrict__ Wr,
                              float* __restrict__ zb, float* __restrict__ tauA,
                              float* __restrict__ rk, uint32_t* flags) {
#pragma clang fp contract(off)
  int tid = threadIdx.x;
  int blk = blockIdx.x;
  if (blk < 512) {
    int idx = blk * 256 + tid;          // idx = b*2048 + t
    int b = idx >> 11, t = idx & 2047;
    float v = V[idx], dd = D[idx];
    float acc = 0.f;
#pragma unroll
    for (int h = 0; h < 5; ++h) {
      float m = fmaf(w1[2 * h + 1], dd, w1[2 * h] * v) + b1[h];
      float th = tanh_xla(m);
      acc = (h == 0) ? (w2[0] * th) : fmaf(w2[h], th, acc);
    }
    float z0 = acc + b2[0];
    uint32_t ka = (t < 1024) ? dH0.a[t] : dH1.a[t - 1024];
    uint32_t kb = (t < 1024) ? dH0.b[t] : dH1.b[t - 1024];
    TF2 o = tf2x32(ka, kb, 0u, (uint32_t)b);
    uint32_t bits = o.x ^ o.y;
    float u = __uint_as_float((bits >> 9) | 0x3f800000u) - 1.0f;
    zb[t * 64 + b] = z0;
    tauA[t * 64 + b] = find_tau(u);
  } else if (blk < 514) {
    int d = (blk - 512) * 256 + tid;    // rk[d] for lag d (1..501), else 0
    float val = 0.f;
    if (d >= 1 && d <= 501) {
      double raw = 7.5 * log((double)(d - 1) + 1.0 + 1e-7);
      float a = 0.f;
      for (int i = 0; i < 30; ++i) {
        double phi = (0.5 * 3.141592653589793) * (double)i;
        float bf;
        if (raw < phi - 3.141592653589793 || raw > phi + 3.141592653589793) bf = 0.f;
        else bf = (float)(0.5 * cos(raw - phi) + 0.5);
        a = fmaf(Wr[i], bf, a);
      }
      val = a;
    }
    rk[d] = val;
  } else {
    if (tid < 80) flags[tid] = 0u;   // flags[0]=stager progress, flags[1+c]=conv done count
  }
}

// ---------------- main kernel ----------------
// block 0: wave0=decision, wave4=stager, waves{1,2,3,5,6,7}=helpers
// blocks 1..232: far-conv (lags 195..501), 4 blocks per chunk, chunks 6..63
__global__ void __launch_bounds__(512, 1)
ap_main_kernel(float* __restrict__ zb, const float* __restrict__ tauA,
               const float* __restrict__ rk, float* __restrict__ zarr,
               ull* __restrict__ sw, uint32_t* flags) {
  // block0 LDS
  __shared__ float lutS[24 * 256];        // octet o: lags 3+8o .. 10+8o, o=0..23
  __shared__ uint32_t snapL[16 * 64];     // snapshot ring: group g&15, per lane; bit j = spike_{16g+15-j}
  __shared__ float comboL[64 * 64];       // combo ring: (s&63, lane) = zb + mid-sum (lags 35..194)
  __shared__ int helperDone[8];
  __shared__ int progL;
  // conv LDS
  __shared__ ull swL[352];
  __shared__ uint32_t colb[64 * 12];
  __shared__ float rkL[512];

  int tid = threadIdx.x;
  int lane = tid & 63;

  if (blockIdx.x == 0) {
    // ---- prologue (all 512 threads) ----
    for (int e = tid; e < 24 * 256; e += 512) {
      int o = e >> 8, vb = e & 255;
      float s = 0.f;
      for (int i = 0; i < 8; ++i)
        if (vb & (1 << i)) s += rk[3 + 8 * o + i];
      lutS[e] = s;
    }
    if (tid < 8) helperDone[tid] = -1;
    if (tid == 0) progL = 0;
    __syncthreads();

    int w = tid >> 6;

    if (w == 0) {
      // ================= DECISION WAVE =================
      float rk1 = rk[1], rk2 = rk[2];
      for (;;) {
        int mn = __hip_atomic_load(&helperDone[1], __ATOMIC_ACQUIRE, __HIP_MEMORY_SCOPE_WORKGROUP);
        mn = min(mn, __hip_atomic_load(&helperDone[2], __ATOMIC_ACQUIRE, __HIP_MEMORY_SCOPE_WORKGROUP));
        mn = min(mn, __hip_atomic_load(&helperDone[3], __ATOMIC_ACQUIRE, __HIP_MEMORY_SCOPE_WORKGROUP));
        mn = min(mn, __hip_atomic_load(&helperDone[5], __ATOMIC_ACQUIRE, __HIP_MEMORY_SCOPE_WORKGROUP));
        mn = min(mn, __hip_atomic_load(&helperDone[6], __ATOMIC_ACQUIRE, __HIP_MEMORY_SCOPE_WORKGROUP));
        mn = min(mn, __hip_atomic_load(&helperDone[7], __ATOMIC_ACQUIRE, __HIP_MEMORY_SCOPE_WORKGROUP));
        if (mn >= 17) break;
        __builtin_amdgcn_s_sleep(1);
      }
      float tauR[8];
#pragma unroll
      for (int q = 0; q < 8; ++q) tauR[q] = tauA[q * 64 + lane];
      float nb[2][4];
      nb[0][0]=nb[0][1]=nb[0][2]=nb[0][3]=0.f;
      nb[1][0]=nb[1][1]=nb[1][2]=nb[1][3]=0.f;
      float cpipe[2];
      cpipe[0] = comboL[lane];
      cpipe[1] = comboL[64 + lane];
      uint32_t m0 = 0;
      float s1f = 0.f, s2f = 0.f;

      for (int t8 = 0; t8 < TT; t8 += 8) {
        if ((t8 & 15) == 0 && t8 != 0) {
          int tgt = t8 + 17; if (tgt > 2047) tgt = 2047;
          for (;;) {
            int mn = __hip_atomic_load(&helperDone[1], __ATOMIC_ACQUIRE, __HIP_MEMORY_SCOPE_WORKGROUP);
            mn = min(mn, __hip_atomic_load(&helperDone[2], __ATOMIC_ACQUIRE, __HIP_MEMORY_SCOPE_WORKGROUP));
            mn = min(mn, __hip_atomic_load(&helperDone[3], __ATOMIC_ACQUIRE, __HIP_MEMORY_SCOPE_WORKGROUP));
            mn = min(mn, __hip_atomic_load(&helperDone[5], __ATOMIC_ACQUIRE, __HIP_MEMORY_SCOPE_WORKGROUP));
            mn = min(mn, __hip_atomic_load(&helperDone[6], __ATOMIC_ACQUIRE, __HIP_MEMORY_SCOPE_WORKGROUP));
            mn = min(mn, __hip_atomic_load(&helperDone[7], __ATOMIC_ACQUIRE, __HIP_MEMORY_SCOPE_WORKGROUP));
            if (mn >= tgt) break;
            __builtin_amdgcn_s_sleep(1);
          }
        }
#pragma unroll
        for (int q = 0; q < 8; ++q) {
          int t = t8 + q;
          int p = q & 1;
          // consume slot t (LUT reads issued at t-2)
          float g = (nb[p][0] + nb[p][1]) + (nb[p][2] + nb[p][3]);
          float z = cpipe[p] + g;
          z = fmaf(rk2, s2f, z);
          z = fmaf(rk1, s1f, z);
          bool sp = z > tauR[q];
          zarr[t * 64 + lane] = z;
          // issue for slot t+2 from PRE-shift m0 (bit j = spike_{t-1-j} -> lag 3+j at t+2)
          nb[p][0] = lutS[(m0 & 255u)];
          nb[p][1] = lutS[256 + ((m0 >> 8) & 255u)];
          nb[p][2] = lutS[512 + ((m0 >> 16) & 255u)];
          nb[p][3] = lutS[768 + (m0 >> 24)];
          cpipe[p] = comboL[(((t + 2) & 63) << 6) + lane];
          // state update
          m0 = (m0 << 1) | (sp ? 1u : 0u);
          s2f = s1f;
          s1f = sp ? 1.0f : 0.0f;
          // tau refill for t+8
          int tn = t + 8; if (tn > 2047) tn = 2047;
          tauR[q] = tauA[tn * 64 + lane];
          // snapshot publish every 16 slots (post-shift: bit j = spike_{t-j})
          if ((t & 15) == 15) {
            snapL[(((t >> 4) & 15) << 6) + lane] = m0;
            if (lane == 0)
              __hip_atomic_store(&progL, t + 1, __ATOMIC_RELEASE, __HIP_MEMORY_SCOPE_WORKGROUP);
          }
        }
      }
      return;
    } else if (w == 4) {
      // ================= STAGER WAVE: snapshots -> global ballots + flags0 =================
      for (int m = 1; m <= 58; ++m) {
        while (__hip_atomic_load(&progL, __ATOMIC_ACQUIRE, __HIP_MEMORY_SCOPE_WORKGROUP) < 32 * m)
          __builtin_amdgcn_s_sleep(4);
        uint32_t sA = snapL[(((2 * m - 2) & 15) << 6) + lane];
        uint32_t sB = snapL[(((2 * m - 1) & 15) << 6) + lane];
#pragma unroll
        for (int i = 0; i < 32; ++i) {
          uint32_t sn = (i < 16) ? sA : sB;
          uint32_t bit = (sn >> (15 - (i & 15))) & 1u;
          ull bal = __ballot(bit != 0u);
          if (lane == 0) sw[32 * (m - 1) + i] = bal;
        }
        if (lane == 0)
          __hip_atomic_store(&flags[0], (uint32_t)m, __ATOMIC_RELEASE, __HIP_MEMORY_SCOPE_AGENT);
      }
      return;
    } else {
      // ================= HELPER WAVES: mid lags 35..194 =================
      int h = (w < 4) ? (w - 1) : (w - 2);   // 0..5
      int qConf = 5;
      for (int s = h; s < TT; s += 6) {
        if (s >= 35) {
          while (__hip_atomic_load(&progL, __ATOMIC_ACQUIRE, __HIP_MEMORY_SCOPE_WORKGROUP) < s - 34)
            __builtin_amdgcn_s_sleep(2);
        }
        int q = s >> 5;
        if (q >= 6 && q > qConf) {
          while (__hip_atomic_load(&flags[1 + q], __ATOMIC_ACQUIRE, __HIP_MEMORY_SCOPE_AGENT) < 4u)
            __builtin_amdgcn_s_sleep(4);
          qConf = q;
        }
        float zv = zb[s * 64 + lane];     // nn + far-conv baseline
        float acc = 0.f;
#pragma unroll
        for (int o = 4; o < 24; ++o) {
          int m = s - (3 + 8 * o);
          float val = 0.f;
          if (m >= 0) {
            uint32_t snap = snapL[(((m >> 4) & 15) << 6) + lane];
            uint32_t byt = (snap >> (15 - (m & 15))) & 255u;
            val = lutS[o * 256 + byt];
          }
          acc += val;
        }
        comboL[((s & 63) << 6) + lane] = zv + acc;
        if (lane == 0)
          __hip_atomic_store(&helperDone[w], s, __ATOMIC_RELEASE, __HIP_MEMORY_SCOPE_WORKGROUP);
      }
      // DEADLOCK FIX: publish completion sentinel (our last own slot may be < 2047,
      // but every slot we own is done, so report past-the-end).
      if (lane == 0)
        __hip_atomic_store(&helperDone[w], 2048, __ATOMIC_RELEASE, __HIP_MEMORY_SCOPE_WORKGROUP);
      return;
    }
  }

  // ================= CONV BLOCKS: far lags 195..501 =================
  int c = 6 + ((int)blockIdx.x - 1) / 4;
  int qq = ((int)blockIdx.x - 1) & 3;
  int T0 = 32 * c + 8 * qq;
  int s0 = T0 - 501;
  if (tid == 0) {
    while ((int)__hip_atomic_load(&flags[0], __ATOMIC_ACQUIRE, __HIP_MEMORY_SCOPE_AGENT) < c - 5)
      __builtin_amdgcn_s_sleep(8);
  }
  __syncthreads();
  for (int i = tid; i < 352; i += 512) {
    int s = s0 + i;
    swL[i] = (s >= 0 && i < 314) ? sw[s] : 0ull;
  }
  rkL[tid] = rk[tid];
  __syncthreads();
  {
    int w = tid >> 6;
#pragma unroll
    for (int rep = 0; rep < 2; ++rep) {
      int W = w + 8 * rep;
      if (W < 11) {
        uint32_t word = 0;
        for (int i2 = 0; i2 < 32; ++i2) {
          ull v = swL[32 * W + i2];
          uint32_t bit = (uint32_t)((v >> lane) & 1ull);
          word |= bit << i2;
        }
        colb[lane * 12 + W] = word;
      }
    }
  }
  __syncthreads();
  {
    int tl = tid >> 6;           // 0..7
    int b = tid & 63;
    uint32_t cw[11];
#pragma unroll
    for (int W = 0; W < 11; ++W) cw[W] = colb[b * 12 + W];
    uint32_t A[10];
#pragma unroll
    for (int W = 0; W < 10; ++W)
      A[W] = __builtin_amdgcn_alignbit(cw[W + 1], cw[W], (uint32_t)tl);
    float acc = 0.f;
#pragma unroll 4
    for (int k = 0; k < 307; ++k) {       // lag = 501-k (501..195); window bit = tl+k, pre-shifted
      float bv = (float)((A[k >> 5] >> (k & 31)) & 1u);
      acc = fmaf(bv, rkL[501 - k], acc);
    }
    int t = T0 + tl;
    float* p = zb + t * 64 + b;
    *p += acc;
  }
  __syncthreads();
  if (tid == 0)
    __hip_atomic_fetch_add(&flags[1 + c], 1u, __ATOMIC_RELEASE, __HIP_MEMORY_SCOPE_AGENT);
}

// ---------------- post kernel ----------------
__global__ void ap_post_kernel(const float* __restrict__ zarr, const float* __restrict__ tauA,
                               float* __restrict__ out) {
#pragma clang fp contract(off)
  int idx = blockIdx.x * 256 + threadIdx.x;   // b*2048 + t
  int b = idx >> 11, t = idx & 2047;
  float z = zarr[t * 64 + b];
  float tau = tauA[t * 64 + b];
  out[idx] = (z > tau) ? 1.0f : 0.0f;
  out[131072 + idx] = 1.0f / (1.0f + __expf(-z));
}

extern "C" void kernel_launch(void* const* d_in, const int* in_sizes, int n_in,
                              void* d_out, int out_size, void* d_ws, size_t ws_size,
                              hipStream_t stream) {
  (void)in_sizes; (void)n_in; (void)out_size; (void)ws_size;
  const float* V  = (const float*)d_in[0];
  const float* D  = (const float*)d_in[1];
  const float* w1 = (const float*)d_in[2];
  const float* b1 = (const float*)d_in[3];
  const float* w2 = (const float*)d_in[4];
  const float* b2 = (const float*)d_in[5];
  const float* Wr = (const float*)d_in[6];

  char* w = (char*)d_ws;
  float*    zb    = (float*)w;                 // [2048*64]  nn + far-conv
  float*    tauA  = (float*)(w + 0x080000);    // [2048*64]
  float*    zarr  = (float*)(w + 0x100000);    // [2048*64]
  ull*      swp   = (ull*)(w + 0x180000);      // [2048]
  float*    rk    = (float*)(w + 0x184000);    // [512]
  uint32_t* flags = (uint32_t*)(w + 0x184800); // [80]

  ap_pre_kernel<<<515, 256, 0, stream>>>(V, D, w1, b1, w2, b2, Wr, zb, tauA, rk, flags);
  ap_main_kernel<<<233, 512, 0, stream>>>(zb, tauA, rk, zarr, swp, flags);
  ap_post_kernel<<<512, 256, 0, stream>>>(zarr, tauA, (float*)d_out);
}

// Round 4
// 445.837 us; speedup vs baseline: 1.6128x; 1.6128x over previous
//
#include <hip/hip_runtime.h>
#include <stdint.h>

typedef unsigned long long ull;

#define TT 2048

// ---------------- compile-time threefry2x32 (JAX semantics) ----------------
struct TF2 { uint32_t x, y; };

constexpr TF2 tf2x32(uint32_t k0, uint32_t k1, uint32_t x0, uint32_t x1) {
  uint32_t ks2 = k0 ^ k1 ^ 0x1BD11BDAu;
  x0 += k0; x1 += k1;
#define TFR_(r) x0 += x1; x1 = __builtin_rotateleft32(x1, r); x1 ^= x0;
  TFR_(13) TFR_(15) TFR_(26) TFR_(6)
  x0 += k1;  x1 += ks2 + 1u;
  TFR_(17) TFR_(29) TFR_(16) TFR_(24)
  x0 += ks2; x1 += k0 + 2u;
  TFR_(13) TFR_(15) TFR_(26) TFR_(6)
  x0 += k0;  x1 += k1 + 3u;
  TFR_(17) TFR_(29) TFR_(16) TFR_(24)
  x0 += k1;  x1 += ks2 + 4u;
  TFR_(13) TFR_(15) TFR_(26) TFR_(6)
  x0 += ks2; x1 += k0 + 5u;
#undef TFR_
  return {x0, x1};
}

struct Half_ { uint32_t a[1024]; uint32_t b[1024]; uint32_t k0, k1; };

constexpr Half_ make_half(uint32_t k0, uint32_t k1) {
  Half_ h{};
  for (int t = 0; t < 1024; ++t) {
    TF2 nk = tf2x32(k0, k1, 0u, 0u);
    TF2 sb = tf2x32(k0, k1, 0u, 1u);
    h.a[t] = sb.x; h.b[t] = sb.y;
    k0 = nk.x; k1 = nk.y;
  }
  h.k0 = k0; h.k1 = k1;
  return h;
}

namespace ckeys {
constexpr Half_ H0 = make_half(0u, 42u);
constexpr Half_ H1 = make_half(H0.k0, H0.k1);
}
__constant__ Half_ dH0 = ckeys::H0;
__constant__ Half_ dH1 = ckeys::H1;

// ---------------- XLA fast-tanh replica ----------------
__device__ __forceinline__ float tanh_xla(float x) {
#pragma clang fp contract(off)
  float ax = fabsf(x);
  float xc = fminf(fmaxf(x, -7.90531110763549805f), 7.90531110763549805f);
  float x2 = xc * xc;
  float p = fmaf(x2, -2.76076847742355e-16f, 2.00018790482477e-13f);
  p = fmaf(x2, p, -8.60467152213735e-11f);
  p = fmaf(x2, p, 5.12229709037114e-08f);
  p = fmaf(x2, p, 1.48572235717979e-05f);
  p = fmaf(x2, p, 6.37261928875436e-04f);
  p = fmaf(x2, p, 4.89352455891786e-03f);
  p = xc * p;
  float q = fmaf(x2, 1.19825839466702e-06f, 1.18534705686654e-04f);
  q = fmaf(x2, q, 2.26843463243900e-03f);
  q = fmaf(x2, q, 4.89352518554385e-03f);
  return (ax < 0.0004f) ? x : (p / q);
}

__device__ __forceinline__ float sig_ref(float z) {
#pragma clang fp contract(off)
  float e = (float)exp(-(double)z);
  return 1.0f / (1.0f + e);
}

__device__ __forceinline__ uint32_t ford(float f) {
  uint32_t x = __float_as_uint(f);
  return (x & 0x80000000u) ? ~x : (x | 0x80000000u);
}
__device__ __forceinline__ float fdec(uint32_t k) {
  uint32_t b = (k & 0x80000000u) ? (k & 0x7fffffffu) : ~k;
  return __uint_as_float(b);
}

// tau = max f32 z with sig_ref(z) <= u  (spike <=> z > tau)
__device__ float find_tau(float u) {
  if (!(u > 0.0f)) return -1.0e30f;
  double zg = log((double)u / (1.0 - (double)u));
  float zgf = (float)zg;
  zgf = fminf(fmaxf(zgf, -90.0f), 90.0f);
  uint32_t kc = ford(zgf);
  uint32_t klo = kc - 96u, khi = kc + 96u;
  if (!(sig_ref(fdec(klo)) <= u)) klo = ford(-95.0f);
  if (!(sig_ref(fdec(khi)) > u))  khi = ford(95.0f);
  while (khi - klo > 1u) {
    uint32_t km = klo + ((khi - klo) >> 1);
    if (sig_ref(fdec(km)) <= u) klo = km; else khi = km;
  }
  return fdec(klo);
}

// ---------------- pre kernel ----------------
__global__ void ap_pre_kernel(const float* __restrict__ V, const float* __restrict__ D,
                              const float* __restrict__ w1, const float* __restrict__ b1,
                              const float* __restrict__ w2, const float* __restrict__ b2,
                              const float* __restrict__ Wr,
                              float* __restrict__ zb, float* __restrict__ tauA,
                              float* __restrict__ rk, uint32_t* flags) {
#pragma clang fp contract(off)
  int tid = threadIdx.x;
  int blk = blockIdx.x;
  if (blk < 512) {
    int idx = blk * 256 + tid;          // idx = b*2048 + t
    int b = idx >> 11, t = idx & 2047;
    float v = V[idx], dd = D[idx];
    float acc = 0.f;
#pragma unroll
    for (int h = 0; h < 5; ++h) {
      float m = fmaf(w1[2 * h + 1], dd, w1[2 * h] * v) + b1[h];
      float th = tanh_xla(m);
      acc = (h == 0) ? (w2[0] * th) : fmaf(w2[h], th, acc);
    }
    float z0 = acc + b2[0];
    uint32_t ka = (t < 1024) ? dH0.a[t] : dH1.a[t - 1024];
    uint32_t kb = (t < 1024) ? dH0.b[t] : dH1.b[t - 1024];
    TF2 o = tf2x32(ka, kb, 0u, (uint32_t)b);
    uint32_t bits = o.x ^ o.y;
    float u = __uint_as_float((bits >> 9) | 0x3f800000u) - 1.0f;
    zb[t * 64 + b] = z0;
    tauA[t * 64 + b] = find_tau(u);
  } else if (blk < 514) {
    int d = (blk - 512) * 256 + tid;    // rk[d] for lag d (1..501), else 0
    float val = 0.f;
    if (d >= 1 && d <= 501) {
      double raw = 7.5 * log((double)(d - 1) + 1.0 + 1e-7);
      float a = 0.f;
      for (int i = 0; i < 30; ++i) {
        double phi = (0.5 * 3.141592653589793) * (double)i;
        float bf;
        if (raw < phi - 3.141592653589793 || raw > phi + 3.141592653589793) bf = 0.f;
        else bf = (float)(0.5 * cos(raw - phi) + 0.5);
        a = fmaf(Wr[i], bf, a);
      }
      val = a;
    }
    rk[d] = val;
  } else {
    // flags[0] = stager progress; flags[1+c] = conv-done count for chunk c (==4 ready)
    if (tid == 0) flags[0] = 0u;
    if (tid >= 1 && tid <= 64) {
      int c = tid - 1;
      flags[tid] = (c <= 4) ? 4u : 0u;   // chunks 0..4 have no far-conv taps
    }
  }
}

// ---------------- main kernel ----------------
// block 0 (512 thr): wave0 = decision (lags 1..82), wave1/wave2 = twins (lags 83..162,
// even/odd 16-slot windows), wave3 = stager (ballots -> sw + flags[0]), waves 4..7 idle.
// blocks 1..236: far conv (lags 163..501), chunks 5..63, 4 blocks/chunk.
__global__ void __launch_bounds__(512, 1)
ap_main_kernel(float* __restrict__ zb, const float* __restrict__ tauA,
               const float* __restrict__ rk, float* __restrict__ zarr,
               ull* __restrict__ sw, uint32_t* flags) {
  // block0 LDS
  __shared__ float lutS[20 * 256];     // o=0..9: bit i -> rk[3+8o+i]; o=10..19: bit i -> rk[3+8o+7-i]
  __shared__ uint32_t snapL[16 * 64];  // group g&15: bit j = spike_{16g+15-j}  (stager)
  __shared__ uint32_t snapA[16 * 64];  // bitreversed: bit j = spike_{16g-16+j} (twins)
  __shared__ float comboL[64 * 64];    // combo ring (s&63, lane): twin sum lags 83..162
  __shared__ int winDone[8];           // generation-tagged: winDone[w&7] == w+1 when window w done
  __shared__ int progLds;              // decision progress (t+1 after window end)
  // conv LDS
  __shared__ ull swL[384];
  __shared__ uint32_t colb[64 * 13];
  __shared__ float rkL[512];

  int tid = threadIdx.x;
  int lane = tid & 63;

  if (blockIdx.x == 0) {
    // ---- prologue: build LUTs (all 512 threads) ----
    for (int e = tid; e < 20 * 256; e += 512) {
      int o = e >> 8, vb = e & 255;
      float s = 0.f;
      if (o < 10) {
        for (int i = 0; i < 8; ++i)
          if (vb & (1 << i)) s += rk[3 + 8 * o + i];
      } else {
        for (int i = 0; i < 8; ++i)
          if (vb & (1 << i)) s += rk[3 + 8 * o + 7 - i];
      }
      lutS[e] = s;
    }
    if (tid < 8) winDone[tid] = 0;
    if (tid == 0) progLds = 0;
    __syncthreads();

    int wv = tid >> 6;

    if (wv == 0) {
      // ================= DECISION WAVE: lags 1..82 =================
      float rk1 = rk[1], rk2 = rk[2];
      // prime zb/tau for windows 0,1 (chunk 0,0 — no conv there)
      float zbR[2][16], tauR[2][16];
#pragma unroll
      for (int q = 0; q < 16; ++q) {
        zbR[0][q]  = zb[q * 64 + lane];
        tauR[0][q] = tauA[q * 64 + lane];
        zbR[1][q]  = zb[1024 + q * 64 + lane];
        tauR[1][q] = tauA[1024 + q * 64 + lane];
      }
      // wait twin window 0, prime combo pipeline (slots 0,1)
      while (__hip_atomic_load(&winDone[0], __ATOMIC_ACQUIRE, __HIP_MEMORY_SCOPE_WORKGROUP) != 1)
        __builtin_amdgcn_s_sleep(1);
      float cpipe[2];
      cpipe[0] = comboL[0 * 64 + lane];
      cpipe[1] = comboL[1 * 64 + lane];
      float l[2][10];
#pragma unroll
      for (int k = 0; k < 10; ++k) { l[0][k] = 0.f; l[1][k] = 0.f; }
      uint32_t m0 = 0, m1 = 0, m2 = 0;
      float s1f = 0.f, s2f = 0.f;

      for (int wp = 0; wp < 64; ++wp) {
#pragma unroll
        for (int half = 0; half < 2; ++half) {
          int w = 2 * wp + half;
          // poll twin for window w+1 (generation-tagged)
          if (w < 127) {
            int slot = (w + 1) & 7, gen = w + 2;
            while (__hip_atomic_load(&winDone[slot], __ATOMIC_ACQUIRE,
                                     __HIP_MEMORY_SCOPE_WORKGROUP) != gen)
              __builtin_amdgcn_s_sleep(1);
          }
          // conv readiness for the chunk we're about to prefetch (2 windows ahead)
          if (half == 0) {
            int c2 = (w + 2) >> 1;
            if (c2 >= 5 && c2 <= 63) {
              while ((int)__hip_atomic_load(&flags[1 + c2], __ATOMIC_ACQUIRE,
                                            __HIP_MEMORY_SCOPE_AGENT) < 4)
                __builtin_amdgcn_s_sleep(2);
            }
          }
          int wl = (w + 2 <= 127) ? (w + 2) : 127;
          const float* zbL  = zb + wl * 1024 + lane;
          const float* tauL = tauA + wl * 1024 + lane;
          float* zarrW = zarr + w * 1024 + lane;
          const float* comboLo = comboL + ((16 * w + 2) & 63) * 64 + lane;
          const float* comboHi = comboL + ((16 * w + 16) & 63) * 64 + lane;
#pragma unroll
          for (int q = 0; q < 16; ++q) {
            int p = q & 1;
            // consume slot t = 16w+q (LUT/combo reads issued at t-2)
            float g = ((l[p][0] + l[p][1]) + (l[p][2] + l[p][3]))
                    + ((l[p][4] + l[p][5]) + (l[p][6] + l[p][7]))
                    + (l[p][8] + l[p][9]);
            float z = (zbR[half][q] + cpipe[p]) + g;
            z = fmaf(rk2, s2f, z);
            z = fmaf(rk1, s1f, z);
            bool sp = z > tauR[half][q];
            zarrW[q * 64] = z;                       // fire-and-forget
            // prefetch zb/tau for window w+2 (element-wise reuse of regs)
            zbR[half][q]  = zbL[q * 64];
            tauR[half][q] = tauL[q * 64];
            // combo read for slot t+2
            cpipe[p] = (q < 14) ? comboLo[q * 64] : comboHi[(q - 14) * 64];
            // LUT reads for slot t+2 from PRE-shift mask (bit j = spike_{t-1-j} -> lag 3+j)
            l[p][0] = lutS[         (m0         & 255u)];
            l[p][1] = lutS[ 256 + ((m0 >> 8 )  & 255u)];
            l[p][2] = lutS[ 512 + ((m0 >> 16)  & 255u)];
            l[p][3] = lutS[ 768 + ( m0 >> 24          )];
            l[p][4] = lutS[1024 + ( m1         & 255u)];
            l[p][5] = lutS[1280 + ((m1 >> 8 )  & 255u)];
            l[p][6] = lutS[1536 + ((m1 >> 16)  & 255u)];
            l[p][7] = lutS[1792 + ( m1 >> 24          )];
            l[p][8] = lutS[2048 + ( m2         & 255u)];
            l[p][9] = lutS[2304 + ((m2 >> 8 )  & 255u)];
            // shift 96-bit history, insert this spike
            m2 = __builtin_amdgcn_alignbit(m2, m1, 31);
            m1 = __builtin_amdgcn_alignbit(m1, m0, 31);
            m0 = (m0 << 1) | (sp ? 1u : 0u);
            s2f = s1f;
            s1f = sp ? 1.0f : 0.0f;
          }
          // end of window: publish snapshots + progress
          snapL[(w & 15) * 64 + lane] = m0;
          snapA[(w & 15) * 64 + lane] = __builtin_bitreverse32(m0);
          if (lane == 0)
            __hip_atomic_store(&progLds, 16 * w + 16, __ATOMIC_RELEASE,
                               __HIP_MEMORY_SCOPE_WORKGROUP);
        }
      }
      return;
    } else if (wv == 1 || wv == 2) {
      // ================= TWIN WAVES: lags 83..162, alternating windows =================
      int par = wv - 1;
      for (int win = par; win < 128; win += 2) {
        if (win >= 4) {
          int tgt = 16 * (win - 3);
          while (__hip_atomic_load(&progLds, __ATOMIC_ACQUIRE,
                                   __HIP_MEMORY_SCOPE_WORKGROUP) < tgt)
            __builtin_amdgcn_s_sleep(1);
        }
        // pack ascending spike bits for groups win-12..win-5 into 4 words
        uint32_t a[8];
#pragma unroll
        for (int j = 0; j < 8; ++j) {
          int g = win - 12 + j;
          a[j] = (g >= 0) ? snapA[(g & 15) * 64 + lane] : 0u;
        }
        uint32_t r[4];
        r[0] = (a[0] >> 16) | (a[1] & 0xFFFF0000u);
        r[1] = (a[2] >> 16) | (a[3] & 0xFFFF0000u);
        r[2] = (a[4] >> 16) | (a[5] & 0xFFFF0000u);
        r[3] = (a[6] >> 16) | (a[7] & 0xFFFF0000u);
        float* cwp = comboL + ((16 * win) & 63) * 64 + lane;
#pragma unroll
        for (int q = 0; q < 16; ++q) {
          float acc = 0.f;
#pragma unroll
          for (int o = 10; o < 20; ++o) {
            int pos = q + 182 - 8 * o;          // low bit = spike_{s-10-8o}
            int k = pos >> 5, sh = pos & 31;
            uint32_t byt;
            if (sh <= 24) byt = (r[k] >> sh) & 255u;
            else          byt = __builtin_amdgcn_alignbit(r[k + 1], r[k], (uint32_t)sh) & 255u;
            acc += lutS[o * 256 + byt];
          }
          cwp[q * 64] = acc;
        }
        if (lane == 0)
          __hip_atomic_store(&winDone[win & 7], win + 1, __ATOMIC_RELEASE,
                             __HIP_MEMORY_SCOPE_WORKGROUP);
      }
      return;
    } else if (wv == 3) {
      // ================= STAGER: snapshots -> ballots -> sw + flags[0] =================
      for (int m = 1; m <= 64; ++m) {
        while (__hip_atomic_load(&progLds, __ATOMIC_ACQUIRE,
                                 __HIP_MEMORY_SCOPE_WORKGROUP) < 32 * m)
          __builtin_amdgcn_s_sleep(2);
        uint32_t sA = snapL[((2 * m - 2) & 15) * 64 + lane];
        uint32_t sB = snapL[((2 * m - 1) & 15) * 64 + lane];
#pragma unroll
        for (int i = 0; i < 32; ++i) {
          uint32_t sn = (i < 16) ? sA : sB;
          uint32_t bit = (sn >> (15 - (i & 15))) & 1u;
          ull bal = __ballot(bit != 0u);
          if (lane == 0) sw[32 * (m - 1) + i] = bal;
        }
        if (lane == 0)
          __hip_atomic_store(&flags[0], (uint32_t)m, __ATOMIC_RELEASE,
                             __HIP_MEMORY_SCOPE_AGENT);
      }
      return;
    }
    return;  // waves 4..7 idle
  }

  // ================= CONV BLOCKS: far lags 163..501 =================
  int c = 5 + ((int)blockIdx.x - 1) / 4;
  int qq = ((int)blockIdx.x - 1) & 3;
  int T0 = 32 * c + 8 * qq;
  int s0 = T0 - 501;
  if (tid == 0) {
    while ((int)__hip_atomic_load(&flags[0], __ATOMIC_ACQUIRE,
                                  __HIP_MEMORY_SCOPE_AGENT) < c - 4)
      __builtin_amdgcn_s_sleep(8);
  }
  __syncthreads();
  for (int i = tid; i < 384; i += 512) {
    int s = s0 + i;
    swL[i] = (s >= 0 && i < 346) ? sw[s] : 0ull;
  }
  rkL[tid] = rk[tid];
  __syncthreads();
  {
    int w8 = tid >> 6;
#pragma unroll
    for (int rep = 0; rep < 2; ++rep) {
      int W = w8 + 8 * rep;
      if (W < 12) {
        uint32_t word = 0;
        for (int i2 = 0; i2 < 32; ++i2) {
          ull v = swL[32 * W + i2];
          uint32_t bit = (uint32_t)((v >> lane) & 1ull);
          word |= bit << i2;
        }
        colb[lane * 13 + W] = word;
      }
    }
  }
  __syncthreads();
  {
    int tl = tid >> 6;           // 0..7
    int b = tid & 63;
    uint32_t cw[12];
#pragma unroll
    for (int W = 0; W < 12; ++W) cw[W] = colb[b * 13 + W];
    uint32_t A[11];
#pragma unroll
    for (int W = 0; W < 11; ++W)
      A[W] = __builtin_amdgcn_alignbit(cw[W + 1], cw[W], (uint32_t)tl);
    float acc = 0.f;
#pragma unroll 4
    for (int k = 0; k < 339; ++k) {   // lag = 501-k (501..163)
      float bv = (float)((A[k >> 5] >> (k & 31)) & 1u);
      acc = fmaf(bv, rkL[501 - k], acc);
    }
    int t = T0 + tl;
    zb[t * 64 + b] += acc;
  }
  __syncthreads();
  if (tid == 0)
    __hip_atomic_fetch_add(&flags[1 + c], 1u, __ATOMIC_RELEASE,
                           __HIP_MEMORY_SCOPE_AGENT);
}

// ---------------- post kernel ----------------
__global__ void ap_post_kernel(const float* __restrict__ zarr, const float* __restrict__ tauA,
                               float* __restrict__ out) {
#pragma clang fp contract(off)
  int idx = blockIdx.x * 256 + threadIdx.x;   // b*2048 + t
  int b = idx >> 11, t = idx & 2047;
  float z = zarr[t * 64 + b];
  float tau = tauA[t * 64 + b];
  out[idx] = (z > tau) ? 1.0f : 0.0f;
  out[131072 + idx] = 1.0f / (1.0f + __expf(-z));
}

extern "C" void kernel_launch(void* const* d_in, const int* in_sizes, int n_in,
                              void* d_out, int out_size, void* d_ws, size_t ws_size,
                              hipStream_t stream) {
  (void)in_sizes; (void)n_in; (void)out_size; (void)ws_size;
  const float* V  = (const float*)d_in[0];
  const float* D  = (const float*)d_in[1];
  const float* w1 = (const float*)d_in[2];
  const float* b1 = (const float*)d_in[3];
  const float* w2 = (const float*)d_in[4];
  const float* b2 = (const float*)d_in[5];
  const float* Wr = (const float*)d_in[6];

  char* w = (char*)d_ws;
  float*    zb    = (float*)w;                 // [2048*64]  nn + far-conv (lags>=163)
  float*    tauA  = (float*)(w + 0x080000);    // [2048*64]
  float*    zarr  = (float*)(w + 0x100000);    // [2048*64]
  ull*      swp   = (ull*)(w + 0x180000);      // [2048]
  float*    rk    = (float*)(w + 0x184000);    // [512]
  uint32_t* flags = (uint32_t*)(w + 0x184800); // [80]

  ap_pre_kernel<<<515, 256, 0, stream>>>(V, D, w1, b1, w2, b2, Wr, zb, tauA, rk, flags);
  ap_main_kernel<<<237, 512, 0, stream>>>(zb, tauA, rk, zarr, swp, flags);
  ap_post_kernel<<<512, 256, 0, stream>>>(zarr, tauA, (float*)d_out);
}